// Round 3
// baseline (257.384 us; speedup 1.0000x reference)
//
#include <hip/hip_runtime.h>
#include <hip/hip_fp16.h>
#include <math.h>

#define NUM_MOVABLE 1000000
#define NUM_FILLER  200000
#define NUM_NODES   1200000
#define NBX 512
#define NBY 512

static constexpr float BSX = 1000.0f / 512.0f;   // bin size, exact (1.953125)
static constexpr float TOTAL_PLACE_AREA = 1000000.0f;
static constexpr float TOTAL_WHITESPACE = 500000.0f;
static constexpr float AREA_STOP  = 0.01f;
static constexpr float ROUTE_STOP = 0.01f;
static constexpr float PIN_STOP   = 0.05f;

// 2x2 neighborhood of both maps at (bx,by), fp16-packed, one cache line hit.
// r0 = (rc[bx][by], rc[bx][by+1]); r1 = (rc[bx+1][by], rc[bx+1][by+1]); same for p.
struct alignas(16) Quad { __half2 r0; __half2 r1; __half2 p0; __half2 p1; };

// ---------------------------------------------------------- block reduce
__device__ __forceinline__ void block_reduce_atomic4(float v0, float v1,
                                                     float v2, float v3,
                                                     float* acc) {
    __shared__ float lds[8][4];
    #pragma unroll
    for (int o = 32; o >= 1; o >>= 1) {
        v0 += __shfl_down(v0, o, 64);
        v1 += __shfl_down(v1, o, 64);
        v2 += __shfl_down(v2, o, 64);
        v3 += __shfl_down(v3, o, 64);
    }
    int wid = threadIdx.x >> 6, lid = threadIdx.x & 63;
    if (lid == 0) { lds[wid][0] = v0; lds[wid][1] = v1; lds[wid][2] = v2; lds[wid][3] = v3; }
    __syncthreads();
    if (threadIdx.x == 0) {
        float s0 = 0.f, s1 = 0.f, s2 = 0.f, s3 = 0.f;
        int nw = blockDim.x >> 6;
        for (int w = 0; w < nw; ++w) { s0 += lds[w][0]; s1 += lds[w][1]; s2 += lds[w][2]; s3 += lds[w][3]; }
        atomicAdd(&acc[0], s0); atomicAdd(&acc[1], s1);
        atomicAdd(&acc[2], s2); atomicAdd(&acc[3], s3);
    }
}

__device__ __forceinline__ float route_val(const float* m, int idx) {
    return fminf(fmaxf(powf(m[idx], 2.5f), 0.5f), 2.0f);
}
__device__ __forceinline__ float pin_val(const float* m, int idx) {
    return fminf(fmaxf(m[idx], (float)(1.0 / 2.5)), 2.5f);
}

// ----------------- prep: build fp16 quad map directly + filler area reduce
__global__ void prep_kernel(const float* __restrict__ route,
                            const float* __restrict__ pin,
                            const float* __restrict__ nsx,
                            const float* __restrict__ nsy,
                            Quad* __restrict__ qmap, float* acc) {
    int i = blockIdx.x * blockDim.x + threadIdx.x;   // grid covers 262144
    if (i < NBX * NBY) {
        int bx = i >> 9, by = i & 511;
        int bx1 = min(bx + 1, NBX - 1), by1 = min(by + 1, NBY - 1);
        int i00 = bx * NBY + by,  i01 = bx * NBY + by1;
        int i10 = bx1 * NBY + by, i11 = bx1 * NBY + by1;
        Quad q;
        q.r0 = __halves2half2(__float2half(route_val(route, i00)),
                              __float2half(route_val(route, i01)));
        q.r1 = __halves2half2(__float2half(route_val(route, i10)),
                              __float2half(route_val(route, i11)));
        q.p0 = __halves2half2(__float2half(pin_val(pin, i00)),
                              __float2half(pin_val(pin, i01)));
        q.p1 = __halves2half2(__float2half(pin_val(pin, i10)),
                              __float2half(pin_val(pin, i11)));
        qmap[i] = q;
    }
    float s = 0.f;
    if (i < NUM_FILLER) {
        int j = NUM_MOVABLE + i;
        s = nsx[j] * nsy[j];
    }
    block_reduce_atomic4(s, 0.f, 0.f, 0.f, acc + 4);
}

// ------------------------------------------------- pass 1: movable gathers
// node size <= 1.2 < bin size 1.953125  =>  only a 2x2 bin window overlaps.
__global__ void pass1_kernel(const float* __restrict__ pos,
                             const float* __restrict__ nsx,
                             const float* __restrict__ nsy,
                             const Quad* __restrict__ qmap,
                             __half* __restrict__ inc, float* acc) {
    float s_old = 0.f, s_inc = 0.f, s_r = 0.f, s_p = 0.f;
    for (int i = blockIdx.x * blockDim.x + threadIdx.x; i < NUM_MOVABLE;
         i += gridDim.x * blockDim.x) {
        float px = pos[i], py = pos[NUM_NODES + i];
        float sx = nsx[i], sy = nsy[i];
        float hix = px + sx, hiy = py + sy;
        int b0x = (int)floorf(px / BSX);
        int b0y = (int)floorf(py / BSX);
        float ex = (float)(b0x + 1) * BSX;   // right edge of first x-bin
        float ey = (float)(b0y + 1) * BSX;
        float wx0 = fminf(hix, ex) - px;     // >= 0 always
        float wx1 = fmaxf(hix - ex, 0.0f);   // 0 when b0x+1 out of range
        float wy0 = fminf(hiy, ey) - py;
        float wy1 = fmaxf(hiy - ey, 0.0f);

        Quad q = qmap[b0x * NBY + b0y];      // one 16B aligned gather
        float2 r0 = __half22float2(q.r0), r1 = __half22float2(q.r1);
        float2 p0 = __half22float2(q.p0), p1 = __half22float2(q.p1);

        float r = wx0 * (wy0 * r0.x + wy1 * r0.y) + wx1 * (wy0 * r1.x + wy1 * r1.y);
        float p = wx0 * (wy0 * p0.x + wy1 * p0.y) + wx1 * (wy0 * p1.x + wy1 * p1.y);

        float old_a = sx * sy;
        float ai = fmaxf(fmaxf(r, p) - old_a, 0.0f);
        inc[i] = __float2half(ai);
        s_old += old_a;
        s_inc += ai;
        s_r += fmaxf(r - old_a, 0.0f);
        s_p += fmaxf(p - old_a, 0.0f);
    }
    block_reduce_atomic4(s_old, s_inc, s_r, s_p, acc);
}

// ---------------------- apply: float4 over 4 nodes, scalar logic inline
__global__ void apply_kernel(const float* __restrict__ pos,
                             const float* __restrict__ nsx,
                             const float* __restrict__ nsy,
                             const __half* __restrict__ inc,
                             const float* __restrict__ acc,
                             float* __restrict__ out) {
    int t = blockIdx.x * blockDim.x + threadIdx.x;
    if (t >= NUM_NODES / 4) return;
    int i = t * 4;   // group never straddles the movable/filler boundary (1e6 % 4 == 0)

    float old_sum = acc[0], inc_sum = acc[1];
    float route_ex = acc[2], pin_ex = acc[3], filler_sum = acc[4];
    float budget = fminf(0.1f * TOTAL_WHITESPACE, TOTAL_PLACE_AREA - old_sum);
    float raw = budget / inc_sum;
    float scale = fminf(fmaxf(raw, 0.0f), 1.0f);
    float scale_eff = (raw <= 0.0f) ? 0.0f : scale;
    float inc_eff = (raw <= 0.0f) ? 0.0f : inc_sum * scale;
    float new_sum = old_sum + inc_eff;
    float area_ratio = inc_eff / old_sum;
    bool route_flag = (route_ex / old_sum) > ROUTE_STOP;
    bool pin_flag = (pin_ex / old_sum) > PIN_STOP;
    bool adjust = (area_ratio > AREA_STOP) && (route_flag || pin_flag);
    bool fcond = adjust && (new_sum + filler_sum > TOTAL_PLACE_AREA);
    float fratio = sqrtf(fmaxf(TOTAL_PLACE_AREA - new_sum, 0.0f) / filler_sum);

    float4 px4 = ((const float4*)pos)[t];
    float4 py4 = ((const float4*)(pos + NUM_NODES))[t];
    float4 sx4 = ((const float4*)nsx)[t];
    float4 sy4 = ((const float4*)nsy)[t];
    float px[4] = {px4.x, px4.y, px4.z, px4.w};
    float py[4] = {py4.x, py4.y, py4.z, py4.w};
    float sx[4] = {sx4.x, sx4.y, sx4.z, sx4.w};
    float sy[4] = {sy4.x, sy4.y, sy4.z, sy4.w};
    float nx[4], ny[4], opx[4], opy[4];

    bool movable = (i < NUM_MOVABLE);
    #pragma unroll
    for (int j = 0; j < 4; ++j) {
        nx[j] = sx[j]; ny[j] = sy[j]; opx[j] = px[j]; opy[j] = py[j];
        if (movable) {
            if (adjust) {
                float old_a = sx[j] * sy[j];
                float na = old_a + __half2float(inc[i + j]) * scale_eff;
                float mr = sqrtf(na / old_a);
                nx[j] = sx[j] * mr; ny[j] = sy[j] * mr;
                opx[j] = px[j] + 0.5f * (sx[j] - nx[j]);
                opy[j] = py[j] + 0.5f * (sy[j] - ny[j]);
            }
        } else if (fcond) {
            nx[j] = sx[j] * fratio; ny[j] = sy[j] * fratio;
            opx[j] = px[j] + 0.5f * (sx[j] - nx[j]);
            opy[j] = py[j] + 0.5f * (sy[j] - ny[j]);
        }
    }
    ((float4*)out)[t]                     = make_float4(opx[0], opx[1], opx[2], opx[3]);
    ((float4*)(out + NUM_NODES))[t]       = make_float4(opy[0], opy[1], opy[2], opy[3]);
    ((float4*)(out + 2 * NUM_NODES))[t]   = make_float4(nx[0], nx[1], nx[2], nx[3]);
    ((float4*)(out + 3 * NUM_NODES))[t]   = make_float4(ny[0], ny[1], ny[2], ny[3]);
}

// ---------------------------------------------------------------- launch
extern "C" void kernel_launch(void* const* d_in, const int* in_sizes, int n_in,
                              void* d_out, int out_size, void* d_ws, size_t ws_size,
                              hipStream_t stream) {
    const float* pos       = (const float*)d_in[0];
    const float* node_sx   = (const float*)d_in[1];
    const float* node_sy   = (const float*)d_in[2];
    // d_in[3] pin_offset_x, d_in[4] pin_offset_y, d_in[5] target_density: unused
    const float* route_map = (const float*)d_in[6];
    const float* pin_map   = (const float*)d_in[7];
    float* out = (float*)d_out;

    char*   ws   = (char*)d_ws;
    Quad*   qmap = (Quad*)ws;                                 // 4 MB quad map
    __half* inc  = (__half*)(ws + sizeof(Quad) * NBX * NBY);  // 2 MB increments
    float*  acc  = (float*)(ws + sizeof(Quad) * NBX * NBY
                               + sizeof(__half) * NUM_MOVABLE);

    hipMemsetAsync(acc, 0, 8 * sizeof(float), stream);
    hipLaunchKernelGGL(prep_kernel, dim3((NBX * NBY + 255) / 256), dim3(256), 0, stream,
                       route_map, pin_map, node_sx, node_sy, qmap, acc);
    hipLaunchKernelGGL(pass1_kernel, dim3(2048), dim3(256), 0, stream,
                       pos, node_sx, node_sy, qmap, inc, acc);
    hipLaunchKernelGGL(apply_kernel, dim3((NUM_NODES / 4 + 255) / 256), dim3(256), 0, stream,
                       pos, node_sx, node_sy, inc, acc, out);
}

// Round 4
// 111.361 us; speedup vs baseline: 2.3113x; 2.3113x over previous
//
#include <hip/hip_runtime.h>
#include <hip/hip_fp16.h>
#include <math.h>

#define NUM_MOVABLE 1000000
#define NUM_FILLER  200000
#define NUM_NODES   1200000
#define NBX 512
#define NBY 512
#define P1_BLOCKS 2048
#define PREP_BLOCKS 1024

static constexpr float BSX = 1000.0f / 512.0f;   // bin size, exact (1.953125)
static constexpr float TOTAL_PLACE_AREA = 1000000.0f;
static constexpr float TOTAL_WHITESPACE = 500000.0f;
static constexpr float AREA_STOP  = 0.01f;
static constexpr float ROUTE_STOP = 0.01f;
static constexpr float PIN_STOP   = 0.05f;

// 2x2 neighborhood of both maps at (bx,by), fp16-packed, one cache line hit.
struct alignas(16) Quad { __half2 r0; __half2 r1; __half2 p0; __half2 p1; };

// ------------------- block reduce of 4 values -> ONE float4 store (no atomics)
__device__ __forceinline__ void block_reduce_store4(float v0, float v1,
                                                    float v2, float v3,
                                                    float4* dst) {
    __shared__ float lds[4][4];
    #pragma unroll
    for (int o = 32; o >= 1; o >>= 1) {
        v0 += __shfl_down(v0, o, 64);
        v1 += __shfl_down(v1, o, 64);
        v2 += __shfl_down(v2, o, 64);
        v3 += __shfl_down(v3, o, 64);
    }
    int wid = threadIdx.x >> 6, lid = threadIdx.x & 63;
    if (lid == 0) { lds[wid][0] = v0; lds[wid][1] = v1; lds[wid][2] = v2; lds[wid][3] = v3; }
    __syncthreads();
    if (threadIdx.x == 0) {
        float s0 = 0.f, s1 = 0.f, s2 = 0.f, s3 = 0.f;
        for (int w = 0; w < 4; ++w) { s0 += lds[w][0]; s1 += lds[w][1]; s2 += lds[w][2]; s3 += lds[w][3]; }
        *dst = make_float4(s0, s1, s2, s3);
    }
}

__device__ __forceinline__ float route_val(const float* m, int idx) {
    return fminf(fmaxf(powf(m[idx], 2.5f), 0.5f), 2.0f);
}
__device__ __forceinline__ float pin_val(const float* m, int idx) {
    return fminf(fmaxf(m[idx], (float)(1.0 / 2.5)), 2.5f);
}

// ----------------- prep: build fp16 quad map + filler-area block partials
__global__ void prep_kernel(const float* __restrict__ route,
                            const float* __restrict__ pin,
                            const float* __restrict__ nsx,
                            const float* __restrict__ nsy,
                            Quad* __restrict__ qmap,
                            float4* __restrict__ fpart) {
    int i = blockIdx.x * blockDim.x + threadIdx.x;   // grid covers 262144
    if (i < NBX * NBY) {
        int bx = i >> 9, by = i & 511;
        int bx1 = min(bx + 1, NBX - 1), by1 = min(by + 1, NBY - 1);
        int i00 = bx * NBY + by,  i01 = bx * NBY + by1;
        int i10 = bx1 * NBY + by, i11 = bx1 * NBY + by1;
        Quad q;
        q.r0 = __halves2half2(__float2half(route_val(route, i00)),
                              __float2half(route_val(route, i01)));
        q.r1 = __halves2half2(__float2half(route_val(route, i10)),
                              __float2half(route_val(route, i11)));
        q.p0 = __halves2half2(__float2half(pin_val(pin, i00)),
                              __float2half(pin_val(pin, i01)));
        q.p1 = __halves2half2(__float2half(pin_val(pin, i10)),
                              __float2half(pin_val(pin, i11)));
        qmap[i] = q;
    }
    float s = 0.f;
    if (i < NUM_FILLER) {
        int j = NUM_MOVABLE + i;
        s = nsx[j] * nsy[j];
    }
    block_reduce_store4(s, 0.f, 0.f, 0.f, fpart + blockIdx.x);
}

// ------------------------------------------------- pass 1: movable gathers
// node size <= 1.2 < bin size 1.953125  =>  only a 2x2 bin window overlaps.
__global__ void pass1_kernel(const float* __restrict__ pos,
                             const float* __restrict__ nsx,
                             const float* __restrict__ nsy,
                             const Quad* __restrict__ qmap,
                             __half* __restrict__ inc,
                             float4* __restrict__ p1part) {
    float s_old = 0.f, s_inc = 0.f, s_r = 0.f, s_p = 0.f;
    for (int i = blockIdx.x * blockDim.x + threadIdx.x; i < NUM_MOVABLE;
         i += gridDim.x * blockDim.x) {
        float px = pos[i], py = pos[NUM_NODES + i];
        float sx = nsx[i], sy = nsy[i];
        float hix = px + sx, hiy = py + sy;
        int b0x = (int)floorf(px / BSX);
        int b0y = (int)floorf(py / BSX);
        float ex = (float)(b0x + 1) * BSX;   // right edge of first x-bin
        float ey = (float)(b0y + 1) * BSX;
        float wx0 = fminf(hix, ex) - px;
        float wx1 = fmaxf(hix - ex, 0.0f);
        float wy0 = fminf(hiy, ey) - py;
        float wy1 = fmaxf(hiy - ey, 0.0f);

        Quad q = qmap[b0x * NBY + b0y];      // one 16B aligned gather
        float2 r0 = __half22float2(q.r0), r1 = __half22float2(q.r1);
        float2 p0 = __half22float2(q.p0), p1 = __half22float2(q.p1);

        float r = wx0 * (wy0 * r0.x + wy1 * r0.y) + wx1 * (wy0 * r1.x + wy1 * r1.y);
        float p = wx0 * (wy0 * p0.x + wy1 * p0.y) + wx1 * (wy0 * p1.x + wy1 * p1.y);

        float old_a = sx * sy;
        float ai = fmaxf(fmaxf(r, p) - old_a, 0.0f);
        inc[i] = __float2half(ai);
        s_old += old_a;
        s_inc += ai;
        s_r += fmaxf(r - old_a, 0.0f);
        s_p += fmaxf(p - old_a, 0.0f);
    }
    block_reduce_store4(s_old, s_inc, s_r, s_p, p1part + blockIdx.x);
}

// ------------- fold: reduce all block partials, compute decision scalars
__global__ void fold_kernel(const float4* __restrict__ p1part,
                            const float4* __restrict__ fpart,
                            float* __restrict__ der) {
    float s0 = 0.f, s1 = 0.f, s2 = 0.f, s3 = 0.f, sf = 0.f;
    for (int b = threadIdx.x; b < P1_BLOCKS; b += 256) {
        float4 v = p1part[b];
        s0 += v.x; s1 += v.y; s2 += v.z; s3 += v.w;
    }
    for (int b = threadIdx.x; b < PREP_BLOCKS; b += 256) sf += fpart[b].x;

    __shared__ float lds[4][5];
    #pragma unroll
    for (int o = 32; o >= 1; o >>= 1) {
        s0 += __shfl_down(s0, o, 64);
        s1 += __shfl_down(s1, o, 64);
        s2 += __shfl_down(s2, o, 64);
        s3 += __shfl_down(s3, o, 64);
        sf += __shfl_down(sf, o, 64);
    }
    int wid = threadIdx.x >> 6, lid = threadIdx.x & 63;
    if (lid == 0) { lds[wid][0] = s0; lds[wid][1] = s1; lds[wid][2] = s2;
                    lds[wid][3] = s3; lds[wid][4] = sf; }
    __syncthreads();
    if (threadIdx.x == 0) {
        float old_sum = 0.f, inc_sum = 0.f, route_ex = 0.f, pin_ex = 0.f, filler_sum = 0.f;
        for (int w = 0; w < 4; ++w) {
            old_sum += lds[w][0]; inc_sum += lds[w][1]; route_ex += lds[w][2];
            pin_ex += lds[w][3]; filler_sum += lds[w][4];
        }
        float budget = fminf(0.1f * TOTAL_WHITESPACE, TOTAL_PLACE_AREA - old_sum);
        float raw = budget / inc_sum;
        float scale = fminf(fmaxf(raw, 0.0f), 1.0f);
        float scale_eff = (raw <= 0.0f) ? 0.0f : scale;
        float inc_eff = (raw <= 0.0f) ? 0.0f : inc_sum * scale;
        float new_sum = old_sum + inc_eff;
        float area_ratio = inc_eff / old_sum;
        bool route_flag = (route_ex / old_sum) > ROUTE_STOP;
        bool pin_flag = (pin_ex / old_sum) > PIN_STOP;
        bool adjust = (area_ratio > AREA_STOP) && (route_flag || pin_flag);
        bool fcond = adjust && (new_sum + filler_sum > TOTAL_PLACE_AREA);
        float fratio = sqrtf(fmaxf(TOTAL_PLACE_AREA - new_sum, 0.0f) / filler_sum);
        der[0] = adjust ? 1.0f : 0.0f;
        der[1] = scale_eff;
        der[2] = fcond ? 1.0f : 0.0f;
        der[3] = fratio;
    }
}

// ---------------------- apply: float4 over 4 nodes, reads der scalars
__global__ void apply_kernel(const float* __restrict__ pos,
                             const float* __restrict__ nsx,
                             const float* __restrict__ nsy,
                             const __half* __restrict__ inc,
                             const float* __restrict__ der,
                             float* __restrict__ out) {
    int t = blockIdx.x * blockDim.x + threadIdx.x;
    if (t >= NUM_NODES / 4) return;
    int i = t * 4;   // groups never straddle the movable/filler boundary

    float adjust = der[0], scale_eff = der[1], fcond = der[2], fratio = der[3];

    float4 px4 = ((const float4*)pos)[t];
    float4 py4 = ((const float4*)(pos + NUM_NODES))[t];
    float4 sx4 = ((const float4*)nsx)[t];
    float4 sy4 = ((const float4*)nsy)[t];
    float px[4] = {px4.x, px4.y, px4.z, px4.w};
    float py[4] = {py4.x, py4.y, py4.z, py4.w};
    float sx[4] = {sx4.x, sx4.y, sx4.z, sx4.w};
    float sy[4] = {sy4.x, sy4.y, sy4.z, sy4.w};
    float nx[4], ny[4], opx[4], opy[4];

    bool movable = (i < NUM_MOVABLE);
    #pragma unroll
    for (int j = 0; j < 4; ++j) {
        nx[j] = sx[j]; ny[j] = sy[j]; opx[j] = px[j]; opy[j] = py[j];
        if (movable) {
            if (adjust > 0.5f) {
                float old_a = sx[j] * sy[j];
                float na = old_a + __half2float(inc[i + j]) * scale_eff;
                float mr = sqrtf(na / old_a);
                nx[j] = sx[j] * mr; ny[j] = sy[j] * mr;
                opx[j] = px[j] + 0.5f * (sx[j] - nx[j]);
                opy[j] = py[j] + 0.5f * (sy[j] - ny[j]);
            }
        } else if (fcond > 0.5f) {
            nx[j] = sx[j] * fratio; ny[j] = sy[j] * fratio;
            opx[j] = px[j] + 0.5f * (sx[j] - nx[j]);
            opy[j] = py[j] + 0.5f * (sy[j] - ny[j]);
        }
    }
    ((float4*)out)[t]                     = make_float4(opx[0], opx[1], opx[2], opx[3]);
    ((float4*)(out + NUM_NODES))[t]       = make_float4(opy[0], opy[1], opy[2], opy[3]);
    ((float4*)(out + 2 * NUM_NODES))[t]   = make_float4(nx[0], nx[1], nx[2], nx[3]);
    ((float4*)(out + 3 * NUM_NODES))[t]   = make_float4(ny[0], ny[1], ny[2], ny[3]);
}

// ---------------------------------------------------------------- launch
extern "C" void kernel_launch(void* const* d_in, const int* in_sizes, int n_in,
                              void* d_out, int out_size, void* d_ws, size_t ws_size,
                              hipStream_t stream) {
    const float* pos       = (const float*)d_in[0];
    const float* node_sx   = (const float*)d_in[1];
    const float* node_sy   = (const float*)d_in[2];
    // d_in[3] pin_offset_x, d_in[4] pin_offset_y, d_in[5] target_density: unused
    const float* route_map = (const float*)d_in[6];
    const float* pin_map   = (const float*)d_in[7];
    float* out = (float*)d_out;

    char*   ws     = (char*)d_ws;
    Quad*   qmap   = (Quad*)ws;                                  // 4 MB quad map
    __half* inc    = (__half*)(ws + sizeof(Quad) * NBX * NBY);   // 2 MB increments
    char*   after  = ws + sizeof(Quad) * NBX * NBY + sizeof(__half) * NUM_MOVABLE;
    float4* p1part = (float4*)after;                             // 2048 float4
    float4* fpart  = p1part + P1_BLOCKS;                         // 1024 float4
    float*  der    = (float*)(fpart + PREP_BLOCKS);              // 4 scalars

    hipLaunchKernelGGL(prep_kernel, dim3(PREP_BLOCKS), dim3(256), 0, stream,
                       route_map, pin_map, node_sx, node_sy, qmap, fpart);
    hipLaunchKernelGGL(pass1_kernel, dim3(P1_BLOCKS), dim3(256), 0, stream,
                       pos, node_sx, node_sy, qmap, inc, p1part);
    hipLaunchKernelGGL(fold_kernel, dim3(1), dim3(256), 0, stream,
                       p1part, fpart, der);
    hipLaunchKernelGGL(apply_kernel, dim3((NUM_NODES / 4 + 255) / 256), dim3(256), 0, stream,
                       pos, node_sx, node_sy, inc, der, out);
}